// Round 5
// baseline (1059.553 us; speedup 1.0000x reference)
//
#include <hip/hip_runtime.h>
#include <hip/hip_bf16.h>
#include <hip/hip_fp16.h>

#define IN_DIM 128
#define HID 64
#define SCAN_TILE 1024  // 256 threads x 4 elements

typedef __hip_bfloat16 bf16;
typedef _Float16 fp16;

// generic element load: is_f32 ? fp32 : bf16 (element-indexed)
__device__ __forceinline__ float loadf(const void* p, size_t i, int isf) {
    if (isf) return ((const float*)p)[i];
    unsigned int u = ((const unsigned short*)p)[i];
    union { unsigned int b; float f; } c;
    c.b = u << 16;
    return c.f;
}

// ---------------- dtype detector (flag=1 means fp32 buffers) ----------------
__global__ void detect_kernel(const unsigned short* __restrict__ feats, int* flag) {
    int lane = threadIdx.x;  // 64 threads
    int bad = 0;
    for (int j = lane; j < 128; j += 64) {
        unsigned short u = feats[j];
        int expo = (u >> 7) & 0xFF;
        if (expo >= 141) bad = 1;
    }
    unsigned long long m = __ballot(bad);
    if (lane == 0) *flag = (__popcll(m) > 4) ? 1 : 0;
}

// ---------------- zero int buffer ----------------
__global__ void zero_kernel(int* __restrict__ p, int n) {
    int i = blockIdx.x * blockDim.x + threadIdx.x;
    int stride = gridDim.x * blockDim.x;
    for (; i < n; i += stride) p[i] = 0;
}

// ---------------- degree count ----------------
__global__ void degree_kernel(const int* __restrict__ src, const int* __restrict__ dst,
                              int* deg_out, int* deg_in, int E) {
    int i = blockIdx.x * blockDim.x + threadIdx.x;
    if (i < E) {
        atomicAdd(&deg_out[src[i]], 1);
        atomicAdd(&deg_in[dst[i]], 1);
    }
}

// ---------------- 3-phase device-wide exclusive scan of deg_in ----------------
__global__ __launch_bounds__(256) void scan1_kernel(const int* __restrict__ deg_in,
                                                    int* __restrict__ row_start,
                                                    int* __restrict__ partials, int N) {
    __shared__ int part[256];
    int tid = threadIdx.x;
    int base = blockIdx.x * SCAN_TILE + tid * 4;
    int v0 = (base + 0 < N) ? deg_in[base + 0] : 0;
    int v1 = (base + 1 < N) ? deg_in[base + 1] : 0;
    int v2 = (base + 2 < N) ? deg_in[base + 2] : 0;
    int v3 = (base + 3 < N) ? deg_in[base + 3] : 0;
    part[tid] = v0 + v1 + v2 + v3;
    __syncthreads();
    for (int off = 1; off < 256; off <<= 1) {
        int add = (tid >= off) ? part[tid - off] : 0;
        __syncthreads();
        part[tid] += add;
        __syncthreads();
    }
    int run = (tid == 0) ? 0 : part[tid - 1];
    if (base + 0 < N) row_start[base + 0] = run;
    run += v0;
    if (base + 1 < N) row_start[base + 1] = run;
    run += v1;
    if (base + 2 < N) row_start[base + 2] = run;
    run += v2;
    if (base + 3 < N) row_start[base + 3] = run;
    if (tid == 255) partials[blockIdx.x] = part[255];
}

__global__ __launch_bounds__(1024) void scan2_kernel(int* __restrict__ partials,
                                                     int* __restrict__ row_start,
                                                     int G, int N) {
    __shared__ int part[1024];
    int tid = threadIdx.x;
    int v = (tid < G) ? partials[tid] : 0;
    part[tid] = v;
    __syncthreads();
    for (int off = 1; off < 1024; off <<= 1) {
        int add = (tid >= off) ? part[tid - off] : 0;
        __syncthreads();
        part[tid] += add;
        __syncthreads();
    }
    if (tid < G) partials[tid] = (tid == 0) ? 0 : part[tid - 1];  // exclusive
    if (tid == 0) row_start[N] = part[1023];                      // total = E
}

__global__ __launch_bounds__(256) void scan3_kernel(const int* __restrict__ partials,
                                                    int* __restrict__ row_start,
                                                    int* __restrict__ cursor, int N) {
    int off = partials[blockIdx.x];
    int base = blockIdx.x * SCAN_TILE + threadIdx.x * 4;
#pragma unroll
    for (int j = 0; j < 4; ++j) {
        int idx = base + j;
        if (idx < N) {
            int r = row_start[idx] + off;
            row_start[idx] = r;
            cursor[idx] = r;
        }
    }
}

// ---------------- CSR fill (edges bucketed by dst) ----------------
__global__ void csr_fill_kernel(const int* __restrict__ src, const int* __restrict__ dst,
                                int* cursor, int* __restrict__ csr_src, int E) {
    int i = blockIdx.x * blockDim.x + threadIdx.x;
    if (i < E) {
        int pos = atomicAdd(&cursor[dst[i]], 1);
        csr_src[pos] = src[i];
    }
}

// ---------------- y1 = (x @ W1) * norm_src   [N,64] fp16 ----------------
__global__ __launch_bounds__(256) void xw1_kernel(const void* __restrict__ feats, size_t xoff,
                                                  const void* __restrict__ W1,
                                                  const int* __restrict__ deg_out,
                                                  const int* __restrict__ flag,
                                                  fp16* __restrict__ y1, int N) {
    __shared__ float W1s[IN_DIM * HID];  // 32 KB
    __shared__ float xs[4][IN_DIM];
    int isf = *flag;
    int tid = threadIdx.x;
    for (int i = tid; i < IN_DIM * HID; i += 256) W1s[i] = loadf(W1, i, isf);
    __syncthreads();
    int wave = tid >> 6, lane = tid & 63;
    int base0 = blockIdx.x * 64;
    for (int it = 0; it < 16; ++it) {
        int n = base0 + wave * 16 + it;
        if (n < N) {
            size_t ro = xoff + (size_t)n * IN_DIM;
            xs[wave][2 * lane]     = loadf(feats, ro + 2 * lane, isf);
            xs[wave][2 * lane + 1] = loadf(feats, ro + 2 * lane + 1, isf);
            float acc = 0.f;
#pragma unroll 16
            for (int k = 0; k < IN_DIM; ++k) acc = fmaf(xs[wave][k], W1s[k * HID + lane], acc);
            float ns = rsqrtf(fmaxf((float)deg_out[n], 1.f));
            y1[(size_t)n * HID + lane] = (fp16)(acc * ns);
        }
    }
}

// masked 8-wide gather-accumulate over one CSR row (fp16 rows, 128B each);
// indices wave-uniform (s_load), 8 row gathers in flight.
__device__ __forceinline__ float row_aggregate(const fp16* __restrict__ y,
                                               const int* __restrict__ csr_src,
                                               int rs, int re, int lane) {
    float acc = 0.f;
    for (int base_e = rs; base_e < re; base_e += 8) {
#pragma unroll
        for (int j = 0; j < 8; ++j) {
            int ee = base_e + j;
            int ec = min(ee, re - 1);          // uniform clamp, safe addr
            int s = csr_src[ec];               // s_load (wave-uniform)
            float a = (float)y[(size_t)s * HID + lane];
            acc += (ee < re) ? a : 0.f;
        }
    }
    return acc;
}

// ---------------- layer1: aggregate + relu + (@W2)*norm_src -> y2 (fp16) ----------------
__global__ __launch_bounds__(256) void agg1_w2_kernel(const fp16* __restrict__ y1,
                                                      const void* __restrict__ W2,
                                                      const void* __restrict__ b1,
                                                      const int* __restrict__ row_start,
                                                      const int* __restrict__ csr_src,
                                                      const int* __restrict__ deg_out,
                                                      const int* __restrict__ flag,
                                                      fp16* __restrict__ y2, int N) {
    __shared__ float W2s[HID * HID];  // 16 KB
    __shared__ float hs[4][HID];
    int isf = *flag;
    int tid = threadIdx.x;
    int wave = tid >> 6, lane = tid & 63;
    for (int i = tid; i < HID * HID; i += 256) W2s[i] = loadf(W2, i, isf);
    float b1l = loadf(b1, lane, isf);
    __syncthreads();
    for (int n = blockIdx.x * 4 + wave; n < N; n += gridDim.x * 4) {
        int nu = __builtin_amdgcn_readfirstlane(n);
        int rs = row_start[nu];
        int re = row_start[nu + 1];
        float acc = row_aggregate(y1, csr_src, rs, re, lane);
        float nd = rsqrtf(fmaxf((float)(re - rs), 1.f));
        hs[wave][lane] = fmaxf(fmaf(acc, nd, b1l), 0.f);  // relu(agg*nd + b1)
        float acc2 = 0.f;
#pragma unroll
        for (int k = 0; k < HID; ++k) acc2 = fmaf(hs[wave][k], W2s[k * HID + lane], acc2);
        float ns = rsqrtf(fmaxf((float)deg_out[nu], 1.f));
        y2[(size_t)nu * HID + lane] = (fp16)(acc2 * ns);
    }
}

// ---------------- layer2: aggregate + bias, then u = h@W3_top, v = h@W3_bot (fp16) ----------------
__global__ __launch_bounds__(256) void agg2_w3_kernel(const fp16* __restrict__ y2,
                                                      const void* __restrict__ W3,
                                                      const void* __restrict__ b2,
                                                      const int* __restrict__ row_start,
                                                      const int* __restrict__ csr_src,
                                                      const int* __restrict__ flag,
                                                      fp16* __restrict__ u,
                                                      fp16* __restrict__ v, int N) {
    __shared__ float W3s[2 * HID * HID];  // 32 KB
    __shared__ float hs[4][HID];
    int isf = *flag;
    int tid = threadIdx.x;
    int wave = tid >> 6, lane = tid & 63;
    for (int i = tid; i < 2 * HID * HID; i += 256) W3s[i] = loadf(W3, i, isf);
    float b2l = loadf(b2, lane, isf);
    __syncthreads();
    for (int n = blockIdx.x * 4 + wave; n < N; n += gridDim.x * 4) {
        int nu = __builtin_amdgcn_readfirstlane(n);
        int rs = row_start[nu];
        int re = row_start[nu + 1];
        float acc = row_aggregate(y2, csr_src, rs, re, lane);
        float nd = rsqrtf(fmaxf((float)(re - rs), 1.f));
        hs[wave][lane] = fmaf(acc, nd, b2l);  // layer2: no relu
        float au = 0.f, av = 0.f;
#pragma unroll
        for (int k = 0; k < HID; ++k) {
            float h = hs[wave][k];
            au = fmaf(h, W3s[k * HID + lane], au);
            av = fmaf(h, W3s[(HID + k) * HID + lane], av);
        }
        u[(size_t)nu * HID + lane] = (fp16)au;
        v[(size_t)nu * HID + lane] = (fp16)av;
    }
}

// ---------------- per-edge scorer: relu(u[s]+v[d]+b3) . W4 + b4 ----------------
__global__ __launch_bounds__(256) void score_kernel(const fp16* __restrict__ u,
                                                    const fp16* __restrict__ v,
                                                    const int* __restrict__ sn,
                                                    const int* __restrict__ dn,
                                                    const void* __restrict__ b3,
                                                    const void* __restrict__ W4,
                                                    const void* __restrict__ b4,
                                                    const int* __restrict__ flag,
                                                    void* __restrict__ out, int E) {
    int isf = *flag;
    int tid = threadIdx.x;
    int lane = tid & 63;
    int gw = __builtin_amdgcn_readfirstlane((blockIdx.x * 256 + tid) >> 6);
    int nw = gridDim.x * 4;
    float b3l = loadf(b3, lane, isf);
    float w4l = loadf(W4, lane, isf);
    float b4v = loadf(b4, 0, isf);
    int i = gw;
    // 4-way unrolled: 8 independent 128B gathers in flight per wave
    for (; i + 3 * nw < E; i += 4 * nw) {
        int i0 = i, i1 = i + nw, i2 = i + 2 * nw, i3 = i + 3 * nw;
        int s0 = sn[i0], d0 = dn[i0];
        int s1 = sn[i1], d1 = dn[i1];
        int s2 = sn[i2], d2 = dn[i2];
        int s3 = sn[i3], d3 = dn[i3];
        float us0 = (float)u[(size_t)s0 * HID + lane], vd0 = (float)v[(size_t)d0 * HID + lane];
        float us1 = (float)u[(size_t)s1 * HID + lane], vd1 = (float)v[(size_t)d1 * HID + lane];
        float us2 = (float)u[(size_t)s2 * HID + lane], vd2 = (float)v[(size_t)d2 * HID + lane];
        float us3 = (float)u[(size_t)s3 * HID + lane], vd3 = (float)v[(size_t)d3 * HID + lane];
        float p0 = fmaxf(us0 + vd0 + b3l, 0.f) * w4l;
        float p1 = fmaxf(us1 + vd1 + b3l, 0.f) * w4l;
        float p2 = fmaxf(us2 + vd2 + b3l, 0.f) * w4l;
        float p3 = fmaxf(us3 + vd3 + b3l, 0.f) * w4l;
#pragma unroll
        for (int off = 32; off > 0; off >>= 1) {
            p0 += __shfl_xor(p0, off, 64);
            p1 += __shfl_xor(p1, off, 64);
            p2 += __shfl_xor(p2, off, 64);
            p3 += __shfl_xor(p3, off, 64);
        }
        if (lane == 0) {
            if (isf) {
                ((float*)out)[i0] = p0 + b4v; ((float*)out)[i1] = p1 + b4v;
                ((float*)out)[i2] = p2 + b4v; ((float*)out)[i3] = p3 + b4v;
            } else {
                ((bf16*)out)[i0] = __float2bfloat16(p0 + b4v);
                ((bf16*)out)[i1] = __float2bfloat16(p1 + b4v);
                ((bf16*)out)[i2] = __float2bfloat16(p2 + b4v);
                ((bf16*)out)[i3] = __float2bfloat16(p3 + b4v);
            }
        }
    }
    for (; i < E; i += nw) {
        int s = sn[i], d = dn[i];
        float h = fmaxf((float)u[(size_t)s * HID + lane] + (float)v[(size_t)d * HID + lane] + b3l, 0.f);
        float p = h * w4l;
#pragma unroll
        for (int off = 32; off > 0; off >>= 1) p += __shfl_xor(p, off, 64);
        if (lane == 0) {
            float r = p + b4v;
            if (isf) ((float*)out)[i] = r;
            else     ((bf16*)out)[i] = __float2bfloat16(r);
        }
    }
}

extern "C" void kernel_launch(void* const* d_in, const int* in_sizes, int n_in,
                              void* d_out, int out_size, void* d_ws, size_t ws_size,
                              hipStream_t stream) {
    const void* feats = d_in[0];
    const void* W1 = d_in[1];
    const void* b1 = d_in[2];
    const void* W2 = d_in[3];
    const void* b2 = d_in[4];
    const void* W3 = d_in[5];
    const void* b3 = d_in[6];
    const void* W4 = d_in[7];
    const void* b4 = d_in[8];
    const int* src_seq = (const int*)d_in[9];
    const int* dst_seq = (const int*)d_in[10];
    const int* src_next = (const int*)d_in[11];
    const int* dst_next = (const int*)d_in[12];

    const int E = in_sizes[11];                // src_next
    const int N = in_sizes[0] / (3 * IN_DIM);  // feats = [T=3, N, 128]
    const int T = in_sizes[9] / E;             // 3

    // only the last snapshot matters: h = h_seq[-1]
    const size_t xoff = (size_t)(T - 1) * N * IN_DIM;  // element offset into feats
    const int* src = src_seq + (size_t)(T - 1) * E;
    const int* dst = dst_seq + (size_t)(T - 1) * E;

    char* w = (char*)d_ws;
    auto alloc = [&](size_t bytes) {
        void* p = (void*)w;
        w += (bytes + 255) & ~(size_t)255;
        return p;
    };
    int* flag      = (int*)alloc(4);
    int* deg_out   = (int*)alloc((size_t)N * 4);
    int* deg_in    = (int*)alloc((size_t)N * 4);
    int* row_start = (int*)alloc((size_t)(N + 1) * 4);
    int* cursor    = (int*)alloc((size_t)N * 4);
    int* partials  = (int*)alloc(1024 * 4);
    int* csr_src   = (int*)alloc((size_t)E * 4);
    fp16* y1       = (fp16*)alloc((size_t)N * HID * 2);
    fp16* y2       = (fp16*)alloc((size_t)N * HID * 2);
    fp16* vv       = (fp16*)alloc((size_t)N * HID * 2);
    fp16* uu       = y1;  // y1 dead after agg1_w2; reuse as u

    const int G = (N + SCAN_TILE - 1) / SCAN_TILE;  // 98 for N=100K (must be <=1024)

    detect_kernel<<<1, 64, 0, stream>>>((const unsigned short*)feats, flag);
    zero_kernel<<<512, 256, 0, stream>>>(deg_out, N);
    zero_kernel<<<512, 256, 0, stream>>>(deg_in, N);
    degree_kernel<<<(E + 255) / 256, 256, 0, stream>>>(src, dst, deg_out, deg_in, E);
    scan1_kernel<<<G, 256, 0, stream>>>(deg_in, row_start, partials, N);
    scan2_kernel<<<1, 1024, 0, stream>>>(partials, row_start, G, N);
    scan3_kernel<<<G, 256, 0, stream>>>(partials, row_start, cursor, N);
    csr_fill_kernel<<<(E + 255) / 256, 256, 0, stream>>>(src, dst, cursor, csr_src, E);
    xw1_kernel<<<(N + 63) / 64, 256, 0, stream>>>(feats, xoff, W1, deg_out, flag, y1, N);
    agg1_w2_kernel<<<2048, 256, 0, stream>>>(y1, W2, b1, row_start, csr_src, deg_out, flag, y2, N);
    agg2_w3_kernel<<<2048, 256, 0, stream>>>(y2, W3, b2, row_start, csr_src, flag, uu, vv, N);
    score_kernel<<<4096, 256, 0, stream>>>(uu, vv, src_next, dst_next, b3, W4, b4, flag,
                                           (void*)d_out, E);
}

// Round 6
// 949.499 us; speedup vs baseline: 1.1159x; 1.1159x over previous
//
#include <hip/hip_runtime.h>
#include <hip/hip_bf16.h>
#include <hip/hip_fp16.h>

#define IN_DIM 128
#define HID 64
#define SCAN_TILE 1024  // 256 threads x 4 elements

typedef __hip_bfloat16 bf16;
typedef _Float16 fp16;
typedef _Float16 h2 __attribute__((ext_vector_type(2)));

// generic element load: is_f32 ? fp32 : bf16 (element-indexed)
__device__ __forceinline__ float loadf(const void* p, size_t i, int isf) {
    if (isf) return ((const float*)p)[i];
    unsigned int u = ((const unsigned short*)p)[i];
    union { unsigned int b; float f; } c;
    c.b = u << 16;
    return c.f;
}

// ---------------- dtype detector (flag=1 means fp32 buffers) ----------------
__global__ void detect_kernel(const unsigned short* __restrict__ feats, int* flag) {
    int lane = threadIdx.x;  // 64 threads
    int bad = 0;
    for (int j = lane; j < 128; j += 64) {
        unsigned short u = feats[j];
        int expo = (u >> 7) & 0xFF;
        if (expo >= 141) bad = 1;
    }
    unsigned long long m = __ballot(bad);
    if (lane == 0) *flag = (__popcll(m) > 4) ? 1 : 0;
}

// ---------------- zero int buffer ----------------
__global__ void zero_kernel(int* __restrict__ p, int n) {
    int i = blockIdx.x * blockDim.x + threadIdx.x;
    int stride = gridDim.x * blockDim.x;
    for (; i < n; i += stride) p[i] = 0;
}

// ---------------- degree count ----------------
__global__ void degree_kernel(const int* __restrict__ src, const int* __restrict__ dst,
                              int* deg_out, int* deg_in, int E) {
    int i = blockIdx.x * blockDim.x + threadIdx.x;
    if (i < E) {
        atomicAdd(&deg_out[src[i]], 1);
        atomicAdd(&deg_in[dst[i]], 1);
    }
}

// ---------------- 3-phase device-wide exclusive scan of deg_in ----------------
__global__ __launch_bounds__(256) void scan1_kernel(const int* __restrict__ deg_in,
                                                    int* __restrict__ row_start,
                                                    int* __restrict__ partials, int N) {
    __shared__ int part[256];
    int tid = threadIdx.x;
    int base = blockIdx.x * SCAN_TILE + tid * 4;
    int v0 = (base + 0 < N) ? deg_in[base + 0] : 0;
    int v1 = (base + 1 < N) ? deg_in[base + 1] : 0;
    int v2 = (base + 2 < N) ? deg_in[base + 2] : 0;
    int v3 = (base + 3 < N) ? deg_in[base + 3] : 0;
    part[tid] = v0 + v1 + v2 + v3;
    __syncthreads();
    for (int off = 1; off < 256; off <<= 1) {
        int add = (tid >= off) ? part[tid - off] : 0;
        __syncthreads();
        part[tid] += add;
        __syncthreads();
    }
    int run = (tid == 0) ? 0 : part[tid - 1];
    if (base + 0 < N) row_start[base + 0] = run;
    run += v0;
    if (base + 1 < N) row_start[base + 1] = run;
    run += v1;
    if (base + 2 < N) row_start[base + 2] = run;
    run += v2;
    if (base + 3 < N) row_start[base + 3] = run;
    if (tid == 255) partials[blockIdx.x] = part[255];
}

__global__ __launch_bounds__(1024) void scan2_kernel(int* __restrict__ partials,
                                                     int* __restrict__ row_start,
                                                     int G, int N) {
    __shared__ int part[1024];
    int tid = threadIdx.x;
    int v = (tid < G) ? partials[tid] : 0;
    part[tid] = v;
    __syncthreads();
    for (int off = 1; off < 1024; off <<= 1) {
        int add = (tid >= off) ? part[tid - off] : 0;
        __syncthreads();
        part[tid] += add;
        __syncthreads();
    }
    if (tid < G) partials[tid] = (tid == 0) ? 0 : part[tid - 1];  // exclusive
    if (tid == 0) row_start[N] = part[1023];                      // total = E
}

__global__ __launch_bounds__(256) void scan3_kernel(const int* __restrict__ partials,
                                                    int* __restrict__ row_start,
                                                    int* __restrict__ cursor, int N) {
    int off = partials[blockIdx.x];
    int base = blockIdx.x * SCAN_TILE + threadIdx.x * 4;
#pragma unroll
    for (int j = 0; j < 4; ++j) {
        int idx = base + j;
        if (idx < N) {
            int r = row_start[idx] + off;
            row_start[idx] = r;
            cursor[idx] = r;
        }
    }
}

// ---------------- CSR fill (edges bucketed by dst) ----------------
__global__ void csr_fill_kernel(const int* __restrict__ src, const int* __restrict__ dst,
                                int* cursor, int* __restrict__ csr_src, int E) {
    int i = blockIdx.x * blockDim.x + threadIdx.x;
    if (i < E) {
        int pos = atomicAdd(&cursor[dst[i]], 1);
        csr_src[pos] = src[i];
    }
}

// ---------------- y1 = (x @ W1) * norm_src   [N,64] fp16 ----------------
__global__ __launch_bounds__(256) void xw1_kernel(const void* __restrict__ feats, size_t xoff,
                                                  const void* __restrict__ W1,
                                                  const int* __restrict__ deg_out,
                                                  const int* __restrict__ flag,
                                                  fp16* __restrict__ y1, int N) {
    __shared__ float W1s[IN_DIM * HID];  // 32 KB
    __shared__ float xs[4][IN_DIM];
    int isf = *flag;
    int tid = threadIdx.x;
    for (int i = tid; i < IN_DIM * HID; i += 256) W1s[i] = loadf(W1, i, isf);
    __syncthreads();
    int wave = tid >> 6, lane = tid & 63;
    int base0 = blockIdx.x * 64;
    for (int it = 0; it < 16; ++it) {
        int n = base0 + wave * 16 + it;
        if (n < N) {
            size_t ro = xoff + (size_t)n * IN_DIM;
            xs[wave][2 * lane]     = loadf(feats, ro + 2 * lane, isf);
            xs[wave][2 * lane + 1] = loadf(feats, ro + 2 * lane + 1, isf);
            float acc = 0.f;
#pragma unroll 16
            for (int k = 0; k < IN_DIM; ++k) acc = fmaf(xs[wave][k], W1s[k * HID + lane], acc);
            float ns = rsqrtf(fmaxf((float)deg_out[n], 1.f));
            y1[(size_t)n * HID + lane] = (fp16)(acc * ns);
        }
    }
}

// masked 8-wide gather-accumulate over one CSR row (fp16 rows, 128B each);
// indices wave-uniform (s_load), 8 row gathers in flight.
__device__ __forceinline__ float row_aggregate(const fp16* __restrict__ y,
                                               const int* __restrict__ csr_src,
                                               int rs, int re, int lane) {
    float acc = 0.f;
    for (int base_e = rs; base_e < re; base_e += 8) {
#pragma unroll
        for (int j = 0; j < 8; ++j) {
            int ee = base_e + j;
            int ec = min(ee, re - 1);          // uniform clamp, safe addr
            int s = csr_src[ec];               // s_load (wave-uniform)
            float a = (float)y[(size_t)s * HID + lane];
            acc += (ee < re) ? a : 0.f;
        }
    }
    return acc;
}

// ---------------- pure gather: h[n] = (relu?)(agg(y)*nd + bias) ----------------
// Zero LDS, low VGPR -> high occupancy; this is the latency-bound part.
__global__ __launch_bounds__(256, 8) void gather_kernel(const fp16* __restrict__ y,
                                                        const void* __restrict__ bias,
                                                        const int* __restrict__ row_start,
                                                        const int* __restrict__ csr_src,
                                                        const int* __restrict__ flag,
                                                        fp16* __restrict__ h,
                                                        int N, int do_relu) {
    int isf = *flag;
    int tid = threadIdx.x;
    int wave = tid >> 6, lane = tid & 63;
    float bl = loadf(bias, lane, isf);
    for (int n = blockIdx.x * 4 + wave; n < N; n += gridDim.x * 4) {
        int nu = __builtin_amdgcn_readfirstlane(n);
        int rs = row_start[nu];
        int re = row_start[nu + 1];
        float acc = row_aggregate(y, csr_src, rs, re, lane);
        float nd = rsqrtf(fmaxf((float)(re - rs), 1.f));
        float r = fmaf(acc, nd, bl);
        if (do_relu) r = fmaxf(r, 0.f);
        h[(size_t)nu * HID + lane] = (fp16)r;
    }
}

// ---------------- dense MLP: y2 = (h @ W2) * norm_src ----------------
__global__ __launch_bounds__(256) void mlp2_kernel(const fp16* __restrict__ h,
                                                   const void* __restrict__ W2,
                                                   const int* __restrict__ deg_out,
                                                   const int* __restrict__ flag,
                                                   fp16* __restrict__ y2, int N) {
    __shared__ float W2s[HID * HID];  // 16 KB
    __shared__ float hs[4][HID];
    int isf = *flag;
    int tid = threadIdx.x;
    int wave = tid >> 6, lane = tid & 63;
    for (int i = tid; i < HID * HID; i += 256) W2s[i] = loadf(W2, i, isf);
    __syncthreads();
    int base0 = blockIdx.x * 64;
    for (int it = 0; it < 16; ++it) {
        int n = base0 + wave * 16 + it;
        if (n < N) {
            hs[wave][lane] = (float)h[(size_t)n * HID + lane];  // wave-private row
            float acc = 0.f;
#pragma unroll
            for (int k = 0; k < HID; ++k) acc = fmaf(hs[wave][k], W2s[k * HID + lane], acc);
            float ns = rsqrtf(fmaxf((float)deg_out[n], 1.f));
            y2[(size_t)n * HID + lane] = (fp16)(acc * ns);
        }
    }
}

// ---------------- dense MLP: u = h@W3_top, v = h@W3_bot ----------------
__global__ __launch_bounds__(256) void mlp3_kernel(const fp16* __restrict__ h,
                                                   const void* __restrict__ W3,
                                                   const int* __restrict__ flag,
                                                   fp16* __restrict__ u,
                                                   fp16* __restrict__ v, int N) {
    __shared__ float W3s[2 * HID * HID];  // 32 KB
    __shared__ float hs[4][HID];
    int isf = *flag;
    int tid = threadIdx.x;
    int wave = tid >> 6, lane = tid & 63;
    for (int i = tid; i < 2 * HID * HID; i += 256) W3s[i] = loadf(W3, i, isf);
    __syncthreads();
    int base0 = blockIdx.x * 64;
    for (int it = 0; it < 16; ++it) {
        int n = base0 + wave * 16 + it;
        if (n < N) {
            hs[wave][lane] = (float)h[(size_t)n * HID + lane];
            float au = 0.f, av = 0.f;
#pragma unroll
            for (int k = 0; k < HID; ++k) {
                float hh = hs[wave][k];
                au = fmaf(hh, W3s[k * HID + lane], au);
                av = fmaf(hh, W3s[(HID + k) * HID + lane], av);
            }
            u[(size_t)n * HID + lane] = (fp16)au;
            v[(size_t)n * HID + lane] = (fp16)av;
        }
    }
}

// ---------------- per-edge scorer, 2 edges/wave packed ----------------
// lanes 0-31 -> edge e=2p, lanes 32-63 -> edge e=2p+1; each lane loads a dword
// (2 fp16 features), so one global_load_dword serves two edges' u-rows.
__global__ __launch_bounds__(256) void score_kernel(const fp16* __restrict__ u,
                                                    const fp16* __restrict__ v,
                                                    const int* __restrict__ sn,
                                                    const int* __restrict__ dn,
                                                    const void* __restrict__ b3,
                                                    const void* __restrict__ W4,
                                                    const void* __restrict__ b4,
                                                    const int* __restrict__ flag,
                                                    void* __restrict__ out, int E) {
    int isf = *flag;
    int tid = threadIdx.x;
    int lane = tid & 63;
    int half = lane >> 5, sub = lane & 31;
    int gw = (blockIdx.x * 256 + tid) >> 6;  // global wave id
    int nw = gridDim.x * 4;
    float b30 = loadf(b3, 2 * sub, isf), b31 = loadf(b3, 2 * sub + 1, isf);
    float w40 = loadf(W4, 2 * sub, isf), w41 = loadf(W4, 2 * sub + 1, isf);
    float b4v = loadf(b4, 0, isf);
    const int P = (E + 1) >> 1;  // pairs

    auto do_pair = [&](int p, bool guard) {
        int e = 2 * p + half;
        int ec = guard ? min(e, E - 1) : e;
        int s = sn[ec], d = dn[ec];
        unsigned pu = ((const unsigned*)(u + (size_t)s * HID))[sub];
        unsigned pv = ((const unsigned*)(v + (size_t)d * HID))[sub];
        h2 hu = __builtin_bit_cast(h2, pu);
        h2 hv = __builtin_bit_cast(h2, pv);
        float h0 = fmaxf((float)hu[0] + (float)hv[0] + b30, 0.f);
        float h1 = fmaxf((float)hu[1] + (float)hv[1] + b31, 0.f);
        float pp = fmaf(h0, w40, h1 * w41);
#pragma unroll
        for (int off = 16; off > 0; off >>= 1) pp += __shfl_xor(pp, off, 64);
        if (sub == 0 && (!guard || e < E)) {
            float r = pp + b4v;
            if (isf) ((float*)out)[e] = r;
            else     ((bf16*)out)[e] = __float2bfloat16(r);
        }
    };

    int p = gw;
    for (; p + 3 * nw < P - 1; p += 4 * nw) {  // last pair handled guarded
        do_pair(p, false);
        do_pair(p + nw, false);
        do_pair(p + 2 * nw, false);
        do_pair(p + 3 * nw, false);
    }
    for (; p < P; p += nw) do_pair(p, true);
}

extern "C" void kernel_launch(void* const* d_in, const int* in_sizes, int n_in,
                              void* d_out, int out_size, void* d_ws, size_t ws_size,
                              hipStream_t stream) {
    const void* feats = d_in[0];
    const void* W1 = d_in[1];
    const void* b1 = d_in[2];
    const void* W2 = d_in[3];
    const void* b2 = d_in[4];
    const void* W3 = d_in[5];
    const void* b3 = d_in[6];
    const void* W4 = d_in[7];
    const void* b4 = d_in[8];
    const int* src_seq = (const int*)d_in[9];
    const int* dst_seq = (const int*)d_in[10];
    const int* src_next = (const int*)d_in[11];
    const int* dst_next = (const int*)d_in[12];

    const int E = in_sizes[11];                // src_next
    const int N = in_sizes[0] / (3 * IN_DIM);  // feats = [T=3, N, 128]
    const int T = in_sizes[9] / E;             // 3

    // only the last snapshot matters: h = h_seq[-1]
    const size_t xoff = (size_t)(T - 1) * N * IN_DIM;  // element offset into feats
    const int* src = src_seq + (size_t)(T - 1) * E;
    const int* dst = dst_seq + (size_t)(T - 1) * E;

    char* w = (char*)d_ws;
    auto alloc = [&](size_t bytes) {
        void* p = (void*)w;
        w += (bytes + 255) & ~(size_t)255;
        return p;
    };
    int* flag      = (int*)alloc(4);
    int* deg_out   = (int*)alloc((size_t)N * 4);
    int* deg_in    = (int*)alloc((size_t)N * 4);
    int* row_start = (int*)alloc((size_t)(N + 1) * 4);
    int* cursor    = (int*)alloc((size_t)N * 4);
    int* partials  = (int*)alloc(1024 * 4);
    int* csr_src   = (int*)alloc((size_t)E * 4);
    fp16* y1       = (fp16*)alloc((size_t)N * HID * 2);
    fp16* y2       = (fp16*)alloc((size_t)N * HID * 2);
    fp16* vv       = (fp16*)alloc((size_t)N * HID * 2);
    fp16* hbuf     = (fp16*)alloc((size_t)N * HID * 2);
    fp16* uu       = y1;  // y1 dead after gather1; reuse as u

    const int G = (N + SCAN_TILE - 1) / SCAN_TILE;  // 98 for N=100K (must be <=1024)
    const int GB = (N + 63) / 64;                   // dense per-node grids

    detect_kernel<<<1, 64, 0, stream>>>((const unsigned short*)feats, flag);
    zero_kernel<<<512, 256, 0, stream>>>(deg_out, N);
    zero_kernel<<<512, 256, 0, stream>>>(deg_in, N);
    degree_kernel<<<(E + 255) / 256, 256, 0, stream>>>(src, dst, deg_out, deg_in, E);
    scan1_kernel<<<G, 256, 0, stream>>>(deg_in, row_start, partials, N);
    scan2_kernel<<<1, 1024, 0, stream>>>(partials, row_start, G, N);
    scan3_kernel<<<G, 256, 0, stream>>>(partials, row_start, cursor, N);
    csr_fill_kernel<<<(E + 255) / 256, 256, 0, stream>>>(src, dst, cursor, csr_src, E);
    xw1_kernel<<<GB, 256, 0, stream>>>(feats, xoff, W1, deg_out, flag, y1, N);
    // layer 1: gather (latency-bound, max occupancy) then dense MLP
    gather_kernel<<<4096, 256, 0, stream>>>(y1, b1, row_start, csr_src, flag, hbuf, N, 1);
    mlp2_kernel<<<GB, 256, 0, stream>>>(hbuf, W2, deg_out, flag, y2, N);
    // layer 2
    gather_kernel<<<4096, 256, 0, stream>>>(y2, b2, row_start, csr_src, flag, hbuf, N, 0);
    mlp3_kernel<<<GB, 256, 0, stream>>>(hbuf, W3, flag, uu, vv, N);
    score_kernel<<<4096, 256, 0, stream>>>(uu, vv, src_next, dst_next, b3, W4, b4, flag,
                                           (void*)d_out, E);
}